// Round 7
// baseline (319.506 us; speedup 1.0000x reference)
//
#include <hip/hip_runtime.h>

// ---------------------------------------------------------------------------
// DoubleLayeredEncoder: 2-layer GCN + PReLU + half-sum. N=100k, E=1.6M.
// R12: transaction-latency polish.
//  - k_ellgemm: nontemporal for all single-touch traffic (edge loads, ELL
//    scatter stores, x loads) -> W1-frags stay hot in L2.
//  - g1g2/g2h: branch-free 16-entry chunks (pad lanes c=0), x8-unrolled
//    gather (8 independent row reads in flight, was 4); nt ELL row reads.
// (kept: R11 packed 64-bit degree atomic; R10 parity interleave; R9 scaling.)
// Pipeline: k_prep -> k_ellgemm -> k_dinv -> k_g1g2 -> k_g2h
// ---------------------------------------------------------------------------

#define ELL_CAP 64
#define WSCALE 8589934592.0f   // 2^33

typedef short short8 __attribute__((ext_vector_type(8)));
typedef float f32x4 __attribute__((ext_vector_type(4)));
typedef int i32x4 __attribute__((ext_vector_type(4)));

__device__ __forceinline__ unsigned bf16rne(float x) {
    unsigned u = __float_as_uint(x);
    return (u + 0x7FFFu + ((u >> 16) & 1u)) >> 16;
}
__device__ __forceinline__ unsigned pack2bf(float a, float b) {
    return bf16rne(a) | (bf16rne(b) << 16);
}
__device__ __forceinline__ void hilo2(float a, float b, unsigned& h, unsigned& l) {
    unsigned ha = bf16rne(a), hb = bf16rne(b);
    float la = a - __uint_as_float(ha << 16);
    float lb = b - __uint_as_float(hb << 16);
    h = ha | (hb << 16);
    l = bf16rne(la) | (bf16rne(lb) << 16);
}
__device__ __forceinline__ float bflo(unsigned u) { return __uint_as_float(u << 16); }
__device__ __forceinline__ float bfhi(unsigned u) { return __uint_as_float(u & 0xFFFF0000u); }

// ---- prep: W1 -> hi/lo B-frags; W2 -> bf16 B-frags; zero cnt64 -------------
// B-frag order: lane l -> col = ct*16 + (l&15), k = s*32 + (l>>4)*8 + 2r+{0,1}
__global__ __launch_bounds__(256) void k_prep(const float* __restrict__ W1,
                                              const float* __restrict__ W2,
                                              unsigned* __restrict__ w1p_hi,
                                              unsigned* __restrict__ w1p_lo,
                                              unsigned* __restrict__ w2p,
                                              unsigned long long* __restrict__ cnt64,
                                              int n) {
    int t = threadIdx.x;
    int bx = blockIdx.x;
    if (bx < 32) {                        // W1: 8192 u32-slots, ct in [0,8)
        int idx = bx * 256 + t;
        int r = idx & 3, l = (idx >> 2) & 63, sct = idx >> 8;
        int s = sct & 3, ct = sct >> 2;
        int col = ct * 16 + (l & 15);
        int k0 = s * 32 + (l >> 4) * 8 + 2 * r;
        unsigned h, lo;
        hilo2(W1[k0 * 128 + col], W1[(k0 + 1) * 128 + col], h, lo);
        w1p_hi[idx] = h;
        w1p_lo[idx] = lo;
    } else if (bx < 48) {                 // W2: 4096 u32-slots, ct in [0,4)
        int idx = (bx - 32) * 256 + t;
        int r = idx & 3, l = (idx >> 2) & 63, sct = idx >> 8;
        int s = sct & 3, ct = sct >> 2;
        int col = ct * 16 + (l & 15);
        int k0 = s * 32 + (l >> 4) * 8 + 2 * r;
        w2p[idx] = pack2bf(W2[k0 * 64 + col], W2[(k0 + 1) * 64 + col]);
    } else {
        int i = (bx - 48) * 256 + t;
        if (i < n) cnt64[i] = 0ULL;
    }
}

// ---- fused: parity-interleaved ELL build + MFMA gemm1 (no LDS) -------------
__global__ __launch_bounds__(256) void k_ellgemm(
    const int* __restrict__ src, const int* __restrict__ dst,
    const int* __restrict__ et, const float* __restrict__ ew,
    unsigned long long* __restrict__ cnt64, int2* __restrict__ ell, int E,
    const float* __restrict__ x,
    const unsigned* __restrict__ w1p_hi, const unsigned* __restrict__ w1p_lo,
    unsigned short* __restrict__ xb1, int n, int G_ell, int G_gemm) {
    int t = threadIdx.x;
    int bid = (int)blockIdx.x;

    // interleave roles: even -> gemm, odd -> ELL (tail = whichever is larger)
    int k2 = 2 * (G_ell < G_gemm ? G_ell : G_gemm);
    bool is_ell;
    int sub;
    if (bid < k2) {
        is_ell = (bid & 1);
        sub = bid >> 1;
    } else {
        is_ell = G_ell > G_gemm;
        sub = (k2 >> 1) + (bid - k2);
    }

    if (is_ell) {
        // ---- ELL build: 4 edges/thread, packed 64-bit atomic, nt I/O ----
        int e0 = (sub * 256 + t) * 4;
        if (e0 + 4 <= E) {
            i32x4 s4 = __builtin_nontemporal_load((const i32x4*)(src + e0));
            i32x4 d4 = __builtin_nontemporal_load((const i32x4*)(dst + e0));
            i32x4 t4 = __builtin_nontemporal_load((const i32x4*)(et + e0));
            f32x4 w4 = __builtin_nontemporal_load((const f32x4*)(ew + e0));
            int p[4];
#pragma unroll
            for (int i = 0; i < 4; i++) {
                unsigned long long pk = (1ULL << 52) |
                                        ((unsigned long long)t4[i] << 40) |
                                        (unsigned long long)(w4[i] * WSCALE);
                p[i] = (int)(atomicAdd(&cnt64[d4[i]], pk) >> 52);
            }
#pragma unroll
            for (int i = 0; i < 4; i++)
                if (p[i] < ELL_CAP) {
                    unsigned long long ev =
                        ((unsigned long long)(unsigned)__float_as_int(w4[i]) << 32) |
                        (unsigned)(s4[i] | (t4[i] << 24));
                    __builtin_nontemporal_store(
                        ev, (unsigned long long*)(ell + d4[i] * ELL_CAP + p[i]));
                }
        } else if (e0 < E) {
            for (int i = 0; i < E - e0; i++) {
                int di = dst[e0 + i];
                int ti = et[e0 + i];
                float wi = ew[e0 + i];
                unsigned long long pk = (1ULL << 52) |
                                        ((unsigned long long)ti << 40) |
                                        (unsigned long long)(wi * WSCALE);
                int p = (int)(atomicAdd(&cnt64[di], pk) >> 52);
                if (p < ELL_CAP)
                    ell[di * ELL_CAP + p] =
                        make_int2(src[e0 + i] | (ti << 24), __float_as_int(wi));
            }
        }
        return;
    }

    // ---- gemm1: 64 rows/block (16/wave), B-frags from L2, no LDS ----
    int l = t & 63, wv = t >> 6;
    int lrow = l & 15, lk = l >> 4;
    int r0 = sub * 64 + wv * 16;
    int row = r0 + lrow;
    bool rok = row < n;
    const float* xbase = x + (size_t)row * 128 + lk * 8;

    f32x4 acc[8];
#pragma unroll
    for (int i = 0; i < 8; i++) acc[i] = (f32x4){0.f, 0.f, 0.f, 0.f};

#pragma unroll
    for (int s = 0; s < 4; s++) {
        f32x4 v0 = (f32x4){0.f, 0.f, 0.f, 0.f};
        f32x4 v1 = (f32x4){0.f, 0.f, 0.f, 0.f};
        if (rok) {
            v0 = __builtin_nontemporal_load((const f32x4*)(xbase + s * 32));
            v1 = __builtin_nontemporal_load((const f32x4*)(xbase + s * 32 + 4));
        }
        union { short8 v; unsigned u[4]; } Ah, Al;
        hilo2(v0[0], v0[1], Ah.u[0], Al.u[0]);
        hilo2(v0[2], v0[3], Ah.u[1], Al.u[1]);
        hilo2(v1[0], v1[1], Ah.u[2], Al.u[2]);
        hilo2(v1[2], v1[3], Ah.u[3], Al.u[3]);
#pragma unroll
        for (int ct = 0; ct < 8; ct++) {
            int off = ((ct * 4 + s) * 64 + l) * 4;
            short8 bh = *(const short8*)(w1p_hi + off);
            short8 bl = *(const short8*)(w1p_lo + off);
            acc[ct] = __builtin_amdgcn_mfma_f32_16x16x32_bf16(Ah.v, bh, acc[ct], 0, 0, 0);
            acc[ct] = __builtin_amdgcn_mfma_f32_16x16x32_bf16(Al.v, bh, acc[ct], 0, 0, 0);
            acc[ct] = __builtin_amdgcn_mfma_f32_16x16x32_bf16(Ah.v, bl, acc[ct], 0, 0, 0);
        }
    }

    // C/D: col = lane&15, row = (lane>>4)*4 + q
#pragma unroll
    for (int q = 0; q < 4; q++) {
        int orow = r0 + lk * 4 + q;
        if (orow < n) {
#pragma unroll
            for (int ct = 0; ct < 8; ct++)
                xb1[(size_t)orow * 128 + ct * 16 + lrow] =
                    (unsigned short)bf16rne(acc[ct][q]);
        }
    }
}

// ---- dinv: unpack degrees, rsqrt, write len, scale xb1 rows (streaming) ----
__global__ __launch_bounds__(256) void k_dinv(const unsigned long long* __restrict__ cnt64,
                                              int* __restrict__ len,
                                              unsigned* __restrict__ xb1,
                                              float* __restrict__ dinv1,
                                              float* __restrict__ dinv2, int n) {
    int t = threadIdx.x;
    int d = blockIdx.x * 16 + (t >> 4);
    int g = t & 15;
    if (d >= n) return;
    unsigned long long pk = cnt64[d];          // broadcast within group
    float wsum = (float)(pk & 0xFFFFFFFFFFULL) * (1.0f / WSCALE);
    int tsum = (int)((pk >> 40) & 0xFFF);
    int c = (int)(pk >> 52);
    float di1 = rsqrtf(1.0f + wsum);
    float di2 = rsqrtf(1.0f + (float)tsum);
    if (g == 0) {
        dinv1[d] = di1;
        dinv2[d] = di2;
        len[d] = min(c, ELL_CAP);
    }
    uint4* p = (uint4*)xb1 + (size_t)d * 16 + g;
    uint4 q = *p;
    q.x = pack2bf(bflo(q.x) * di1, bfhi(q.x) * di1);
    q.y = pack2bf(bflo(q.y) * di1, bfhi(q.y) * di1);
    q.z = pack2bf(bflo(q.z) * di1, bfhi(q.z) * di1);
    q.w = pack2bf(bflo(q.w) * di1, bfhi(q.w) * di1);
    *p = q;
}

// ---- gather layer 1 (coeff = raw w) + bias/PReLU + MFMA gemm2 -> xb2s ------
// 16 nodes/block, 16 lanes/node (8 ch/lane). Branch-free 16-chunks, x8 MLP.
__global__ __launch_bounds__(256) void k_g1g2(const int* __restrict__ len_,
                                              const int2* __restrict__ ell,
                                              const unsigned* __restrict__ xb1,
                                              const float* __restrict__ dinv1,
                                              const float* __restrict__ dinv2,
                                              const float* __restrict__ b,
                                              const float* __restrict__ alpha,
                                              const unsigned* __restrict__ w2p,
                                              unsigned short* __restrict__ xb2,
                                              int n) {
    __shared__ __align__(16) unsigned hsh[16 * 64];   // h1 hi kpairs, 4KB
    __shared__ __align__(16) unsigned hsl[16 * 64];   // h1 lo kpairs, 4KB
    int t = threadIdx.x;
    int nl = t >> 4;                     // node slot 0..15
    int g = t & 15;                      // 8 channels: [8g, 8g+8)
    int d = blockIdx.x * 16 + nl;
    bool active = d < n;
    int len = active ? len_[d] : 0;
    const int2* row = ell + (size_t)d * ELL_CAP;
    const uint4* x4 = (const uint4*)xb1;  // [N][16] uint4 (pre-scaled rows)

    float di = active ? dinv1[d] : 0.f;
    uint4 sq = active ? x4[(size_t)d * 16 + g] : make_uint4(0, 0, 0, 0);

    float a[8] = {0.f, 0.f, 0.f, 0.f, 0.f, 0.f, 0.f, 0.f};
    auto acc8 = [&](uint4 q, float c) {
        a[0] += bflo(q.x) * c; a[1] += bfhi(q.x) * c;
        a[2] += bflo(q.y) * c; a[3] += bfhi(q.y) * c;
        a[4] += bflo(q.z) * c; a[5] += bfhi(q.z) * c;
        a[6] += bflo(q.w) * c; a[7] += bfhi(q.w) * c;
    };
    for (int k0 = 0; k0 < len; k0 += 16) {
        int kk = k0 + g;
        int ex = 0;
        float cf = 0.f;
        if (kk < len) {
            unsigned long long ev =
                __builtin_nontemporal_load((const unsigned long long*)(row + kk));
            ex = (int)(unsigned)ev;
            cf = __uint_as_float((unsigned)(ev >> 32));
        }
        // pad lanes (kk>=len): ex=0 -> row 0 load (L2-hit), cf=0 -> adds 0.
#pragma unroll
        for (int jb = 0; jb < 16; jb += 8) {
            int ss[8];
            float cc[8];
#pragma unroll
            for (int u = 0; u < 8; u++) {
                ss[u] = __shfl(ex, jb + u, 16) & 0xFFFFFF;
                cc[u] = __shfl(cf, jb + u, 16);
            }
            uint4 qq[8];
#pragma unroll
            for (int u = 0; u < 8; u++) qq[u] = x4[(size_t)ss[u] * 16 + g];
#pragma unroll
            for (int u = 0; u < 8; u++) acc8(qq[u], cc[u]);
        }
    }

    if (active) {
        // h1 = di*(a + xb1s[d]) + b, then PReLU
        float sv[8] = {bflo(sq.x), bfhi(sq.x), bflo(sq.y), bfhi(sq.y),
                       bflo(sq.z), bfhi(sq.z), bflo(sq.w), bfhi(sq.w)};
        int c8 = g << 3;
        float4 b0 = *(const float4*)&b[c8];
        float4 b1v = *(const float4*)&b[c8 + 4];
        float4 av0 = *(const float4*)&alpha[c8];
        float4 av1 = *(const float4*)&alpha[c8 + 4];
        float bb[8] = {b0.x, b0.y, b0.z, b0.w, b1v.x, b1v.y, b1v.z, b1v.w};
        float aa[8] = {av0.x, av0.y, av0.z, av0.w, av1.x, av1.y, av1.z, av1.w};
        float v[8];
#pragma unroll
        for (int i = 0; i < 8; i++) {
            float vv = di * (a[i] + sv[i]) + bb[i];
            v[i] = vv >= 0.f ? vv : aa[i] * vv;
        }
        unsigned H[4], L[4];
        hilo2(v[0], v[1], H[0], L[0]);
        hilo2(v[2], v[3], H[1], L[1]);
        hilo2(v[4], v[5], H[2], L[2]);
        hilo2(v[6], v[7], H[3], L[3]);
        unsigned byte = ((unsigned)(nl * 256 + g * 16)) ^ (((unsigned)nl & 7u) << 4);
        *(uint4*)((char*)hsh + byte) = make_uint4(H[0], H[1], H[2], H[3]);
        *(uint4*)((char*)hsl + byte) = make_uint4(L[0], L[1], L[2], L[3]);
    }
    __syncthreads();

    // gemm2: wave w -> cols 16w..16w+15, rows = 16 nodes
    int l = t & 63, w = t >> 6;
    int arow = l & 15, kg = l >> 4;
    f32x4 acc = (f32x4){0.f, 0.f, 0.f, 0.f};
#pragma unroll
    for (int s = 0; s < 4; s++) {
        unsigned byte = ((unsigned)(arow * 256 + s * 64 + kg * 16)) ^
                        (((unsigned)arow & 7u) << 4);
        short8 Ah = *(const short8*)((char*)hsh + byte);
        short8 Al = *(const short8*)((char*)hsl + byte);
        short8 B = *(const short8*)(w2p + ((w * 4 + s) * 64 + l) * 4);
        acc = __builtin_amdgcn_mfma_f32_16x16x32_bf16(Ah, B, acc, 0, 0, 0);
        acc = __builtin_amdgcn_mfma_f32_16x16x32_bf16(Al, B, acc, 0, 0, 0);
    }
    int col = w * 16 + arow;
#pragma unroll
    for (int q = 0; q < 4; q++) {
        int node = blockIdx.x * 16 + kg * 4 + q;
        if (node < n) {
            float di2 = dinv2[node];
            xb2[(size_t)node * 64 + col] = (unsigned short)bf16rne(di2 * acc[q]);
        }
    }
}

// ---- gather layer 2 (coeff = etype) + bias/PReLU + half-sum readout --------
__global__ __launch_bounds__(256) void k_g2h(const int* __restrict__ len_,
                                             const int2* __restrict__ ell,
                                             const unsigned* __restrict__ xb2,
                                             const float* __restrict__ dinv2,
                                             const float* __restrict__ b,
                                             const float* __restrict__ alpha,
                                             float* __restrict__ out, int half) {
    __shared__ float fs[8 * 64];         // second-half results, 2 KB
    int t = threadIdx.x;
    int slot = t >> 4;                   // 0..15
    int g = t & 15;
    int base = blockIdx.x * 8;
    int j = base + ((slot < 8) ? slot : (slot - 8));
    int d = (slot < 8) ? j : (j + half);
    bool active = j < half;
    int len = active ? len_[d] : 0;
    const int2* row = ell + (size_t)d * ELL_CAP;
    const uint2* x2 = (const uint2*)xb2;  // [N][16] uint2 (pre-scaled rows)

    float di = active ? dinv2[d] : 0.f;
    uint2 sq = active ? x2[(size_t)d * 16 + g] : make_uint2(0, 0);

    float a0 = 0.f, a1v_ = 0.f, a2v_ = 0.f, a3 = 0.f;
    auto acc4 = [&](uint2 q, float c) {
        a0 += bflo(q.x) * c; a1v_ += bfhi(q.x) * c;
        a2v_ += bflo(q.y) * c; a3 += bfhi(q.y) * c;
    };
    for (int k0 = 0; k0 < len; k0 += 16) {
        int kk = k0 + g;
        int ex = 0;
        if (kk < len)
            ex = __builtin_nontemporal_load((const int*)(row + kk));
#pragma unroll
        for (int jb = 0; jb < 16; jb += 8) {
            int ee[8];
#pragma unroll
            for (int u = 0; u < 8; u++) ee[u] = __shfl(ex, jb + u, 16);
            uint2 qq[8];
            float cc[8];
#pragma unroll
            for (int u = 0; u < 8; u++) {
                unsigned tt = ((unsigned)ee[u]) >> 24;
                cc[u] = (float)tt;
                qq[u] = make_uint2(0, 0);
                if (tt) qq[u] = x2[(size_t)(ee[u] & 0xFFFFFF) * 16 + g];
            }
#pragma unroll
            for (int u = 0; u < 8; u++) acc4(qq[u], cc[u]);
        }
    }

    float f0 = 0.f, f1 = 0.f, f2 = 0.f, f3 = 0.f;
    if (active) {
        float s0 = bflo(sq.x), s1 = bfhi(sq.x), s2 = bflo(sq.y), s3 = bfhi(sq.y);
        int c4 = g << 2;
        float4 bv = *(const float4*)&b[c4];
        float4 av = *(const float4*)&alpha[c4];
        f0 = di * (a0 + s0) + bv.x; f0 = f0 >= 0.f ? f0 : av.x * f0;
        f1 = di * (a1v_ + s1) + bv.y; f1 = f1 >= 0.f ? f1 : av.y * f1;
        f2 = di * (a2v_ + s2) + bv.z; f2 = f2 >= 0.f ? f2 : av.z * f2;
        f3 = di * (a3 + s3) + bv.w; f3 = f3 >= 0.f ? f3 : av.w * f3;
    }
    if (slot >= 8)
        *(float4*)&fs[(slot - 8) * 64 + (g << 2)] = make_float4(f0, f1, f2, f3);
    __syncthreads();
    if (slot < 8 && active) {
        float4 p = *(const float4*)&fs[slot * 64 + (g << 2)];
        ((float4*)out)[j * 16 + g] = make_float4(0.5f * (f0 + p.x), 0.5f * (f1 + p.y),
                                                 0.5f * (f2 + p.z), 0.5f * (f3 + p.w));
    }
}

extern "C" void kernel_launch(void* const* d_in, const int* in_sizes, int n_in,
                              void* d_out, int out_size, void* d_ws, size_t ws_size,
                              hipStream_t stream) {
    const float* x  = (const float*)d_in[0];
    const int*   ei = (const int*)d_in[1];
    const float* ew = (const float*)d_in[2];
    const int*   et = (const int*)d_in[3];
    const float* W1 = (const float*)d_in[4];
    const float* b1 = (const float*)d_in[5];
    const float* a1 = (const float*)d_in[6];
    const float* W2 = (const float*)d_in[7];
    const float* b2 = (const float*)d_in[8];
    const float* a2 = (const float*)d_in[9];

    const int N = in_sizes[0] / 128;   // 100000
    const int E = in_sizes[1] / 2;     // 1600000
    const int* src = ei;
    const int* dst = ei + E;

    // Workspace (u32 words), ~92 MB + 80KB frags:
    //   dinv1 N | dinv2 N | xb1 64N | xb2 32N | len N | cnt64 2N | ell 128N
    //   | w1p_hi 8192 | w1p_lo 8192 | w2p 4096
    float*    ws     = (float*)d_ws;
    float*    dinv1  = ws;
    float*    dinv2  = dinv1 + N;
    unsigned* xb1    = (unsigned*)(dinv2 + N);
    unsigned* xb2    = xb1 + (size_t)N * 64;
    int*      len    = (int*)(xb2 + (size_t)N * 32);
    unsigned long long* cnt64 = (unsigned long long*)(len + N);
    int2*     ell    = (int2*)(cnt64 + N);
    unsigned* w1p_hi = (unsigned*)(ell + (size_t)N * ELL_CAP);
    unsigned* w1p_lo = w1p_hi + 8192;
    unsigned* w2p    = w1p_lo + 8192;

    const int G_ell  = (E / 4 + 255) / 256;   // 1563
    const int G_gemm = (N + 63) / 64;         // 1563

    k_prep<<<48 + (N + 255) / 256, 256, 0, stream>>>(W1, W2, w1p_hi, w1p_lo,
                                                     w2p, cnt64, N);

    k_ellgemm<<<G_ell + G_gemm, 256, 0, stream>>>(
        src, dst, et, ew, cnt64, ell, E, x, w1p_hi, w1p_lo,
        (unsigned short*)xb1, N, G_ell, G_gemm);

    k_dinv<<<(N + 15) / 16, 256, 0, stream>>>(cnt64, len, xb1, dinv1, dinv2, N);

    k_g1g2<<<(N + 15) / 16, 256, 0, stream>>>(len, ell, xb1, dinv1, dinv2,
                                              b1, a1, w2p,
                                              (unsigned short*)xb2, N);

    k_g2h<<<(N / 2 + 7) / 8, 256, 0, stream>>>(len, ell, xb2, dinv2, b2, a2,
                                               (float*)d_out, N / 2);
}